// Round 13
// baseline (943.830 us; speedup 1.0000x reference)
//
#include <hip/hip_runtime.h>
#include <hip/hip_fp16.h>
#include <hip/hip_cooperative_groups.h>

namespace cg = cooperative_groups;

#define N_NODES 50000
#define N_EDGES 800000
#define N_TILES (N_EDGES / 64)                 // 12,500

typedef short  bf16x8 __attribute__((ext_vector_type(8)));
typedef float  f32x4  __attribute__((ext_vector_type(4)));
typedef _Float16 h16x2 __attribute__((ext_vector_type(2)));

// 32-bit fixed point in d_out: scale 2^22. VALIDATED rounds 8/9 (tripwire-safe:
// integer atomics associative+commutative; absmax 0.015625).
#define FXP32_SCALE 4194304.0f                 // 2^22
#define FXP32_INV   2.384185791015625e-07f     // 2^-22

#define WSB_BYTES   (36864 * 2)                // 73,728 B

__device__ __forceinline__ unsigned short f2bf(float f) {
    unsigned u = __float_as_uint(f);
    u += 0x7FFF + ((u >> 16) & 1);          // RNE
    return (unsigned short)(u >> 16);
}

__device__ __forceinline__ f32x4 fma4(f32x4 a, f32x4 b, f32x4 c) {
    f32x4 r;
    r[0] = fmaf(a[0], b[0], c[0]);
    r[1] = fmaf(a[1], b[1], c[1]);
    r[2] = fmaf(a[2], b[2], c[2]);
    r[3] = fmaf(a[3], b[3], c[3]);
    return r;
}

#if __has_builtin(__builtin_amdgcn_fdot2)
__device__ __forceinline__ float FDOT2(h16x2 a, h16x2 b, float c) {
    return __builtin_amdgcn_fdot2(a, b, c, false);
}
#else
__device__ __forceinline__ float FDOT2(h16x2 a, h16x2 b, float c) {
    return fmaf((float)a.x, (float)b.x, fmaf((float)a.y, (float)b.y, c));
}
#endif

// ---------------------------------------------------------------------------
// shared device helpers: pack work-items and finalize element
// ---------------------------------------------------------------------------
__device__ __forceinline__ void pack_item(int p,
                                          const float* __restrict__ W2,
                                          const float* __restrict__ W1,
                                          unsigned short* __restrict__ wsB,
                                          unsigned* __restrict__ w1p) {
    if (p < 36864) {
        int j    = p & 7;
        int lane = (p >> 3) & 63;
        int ks   = (p >> 9) & 1;
        int nt   = p >> 10;
        int k = ks * 32 + (lane >> 4) * 8 + j;
        int n = nt * 16 + (lane & 15);
        wsB[p] = f2bf(W2[k * 576 + n]);
    } else {
        int idx = p - 36864;               // < 512
        int kk  = idx >> 6;
        int i   = idx & 63;
        __half lo = __float2half(W1[(2*kk)     * 64 + i]);
        __half hi = __float2half(W1[(2*kk + 1) * 64 + i]);
        w1p[idx] = (unsigned)__half_as_ushort(lo)
                 | ((unsigned)__half_as_ushort(hi) << 16);
    }
}

__device__ __forceinline__ float4 finalize4(float4 v) {
    float4 f;
    f.x = (float)__float_as_int(v.x) * FXP32_INV;
    f.y = (float)__float_as_int(v.y) * FXP32_INV;
    f.z = (float)__float_as_int(v.z) * FXP32_INV;
    f.w = (float)__float_as_int(v.w) * FXP32_INV;
    return f;
}

// ---------------------------------------------------------------------------
// conv_tile: one 64-edge tile, one wave. r9-verified body verbatim.
// Ends with a full lgkm drain so a following tile's h-writes cannot
// WAR-race this tile's epilogue LDS reads.
// ---------------------------------------------------------------------------
__device__ __forceinline__ void conv_tile(
    int tile, int lane,
    const float* __restrict__ pos,
    const float* __restrict__ f_in,
    const int*   __restrict__ esrc,
    const int*   __restrict__ edst,
    const unsigned* __restrict__ w1p,
    const unsigned short* __restrict__ wsB,
    int*         __restrict__ f_out_i,
    char*        my)
{
    float* shf = (float*)my;
    const int e = tile * 64 + lane;

    const int s = esrc[e];
    const int d = edst[e];

    // early B prefetch: chunks 0 and 1
    const bf16x8* wsBv = (const bf16x8*)wsB;
    bf16x8 bc0 = wsBv[lane],        bc1 = wsBv[64 + lane];
    bf16x8 bn0 = wsBv[128 + lane],  bn1 = wsBv[192 + lane];
    bf16x8 b20, b21;

    // --- geometry -----------------------------------------------------------
    float px = pos[3*d+0] - pos[3*s+0];
    float py = pos[3*d+1] - pos[3*s+1];
    float pz = pos[3*d+2] - pos[3*s+2];
    float r  = sqrtf(px*px + py*py + pz*pz + 1e-12f);
    float inv_r = __builtin_amdgcn_rcpf(r);
    float ux = px*inv_r, uy = py*inv_r, uz = pz*inv_r;
    const float SQ3 = 1.7320508075688772f;
    float shx = SQ3*ux, shy = SQ3*uy, shz = SQ3*uz;

    // --- x = f_in[src] ------------------------------------------------------
    float x0[16], x1[24], dot[8];
    {
        const float4* xg4 = reinterpret_cast<const float4*>(f_in + (size_t)s * 40);
        float xr[40];
        #pragma unroll
        for (int q8 = 0; q8 < 10; ++q8) {
            float4 v = xg4[q8];
            xr[4*q8+0] = v.x; xr[4*q8+1] = v.y; xr[4*q8+2] = v.z; xr[4*q8+3] = v.w;
        }
        #pragma unroll
        for (int i = 0; i < 16; ++i) x0[i] = xr[i];
        #pragma unroll
        for (int i = 0; i < 24; ++i) x1[i] = xr[16+i];
        #pragma unroll
        for (int u = 0; u < 8; ++u)
            dot[u] = x1[3*u+0]*ux + x1[3*u+1]*uy + x1[3*u+2]*uz;  // = inv_s3*(x1.sh1)
    }

    // --- radial embedding (dense, verified) ---------------------------------
    const float A = 1.14136f * 7.38905609893065f;   // 1.14136 * e^2
    const float inv_step = 17.0f / 5.0f;
    float emb[16];
    #pragma unroll
    for (int k = 0; k < 16; ++k) {
        float dd  = r * inv_step - (float)(k + 1);
        float d2v = dd * dd;
        float arg = -2.0f * __builtin_amdgcn_rcpf(1.0f - d2v);
        float val = A * __expf(arg);
        emb[k] = (d2v < 1.0f) ? val : 0.0f;
    }

    // --- h = silu(emb @ W1) via f16 dot2 (verified v7/v9) --------------------
    unsigned ep[8];
    #pragma unroll
    for (int kk = 0; kk < 8; ++kk) {
        __half lo = __float2half(emb[2*kk]);
        __half hi = __float2half(emb[2*kk+1]);
        ep[kk] = (unsigned)__half_as_ushort(lo)
               | ((unsigned)__half_as_ushort(hi) << 16);
    }
    float h[64];
    #pragma unroll
    for (int i = 0; i < 64; ++i) h[i] = 0.f;
    #pragma unroll
    for (int kk = 0; kk < 8; ++kk) {
        h16x2 ev = __builtin_bit_cast(h16x2, ep[kk]);
        const unsigned* wrow = w1p + kk * 64;
        #pragma unroll
        for (int i = 0; i < 64; ++i) {
            h16x2 wv = __builtin_bit_cast(h16x2, wrow[i]);
            h[i] = FDOT2(ev, wv, h[i]);
        }
    }
    #pragma unroll
    for (int i = 0; i < 64; ++i) {
        float z = h[i];
        h[i] = z * __builtin_amdgcn_rcpf(1.0f + __expf(-z));
    }

    // --- stage h -> LDS [edge][k] bf16, row stride 144 B -------------------
    {
        unsigned int hp[32];
        #pragma unroll
        for (int i = 0; i < 32; ++i)
            hp[i] = (unsigned)f2bf(h[2*i]) | ((unsigned)f2bf(h[2*i+1]) << 16);
        uint4* hrow = (uint4*)(my + lane * 144);
        #pragma unroll
        for (int g = 0; g < 8; ++g)
            hrow[g] = make_uint4(hp[4*g], hp[4*g+1], hp[4*g+2], hp[4*g+3]);
    }
    asm volatile("s_waitcnt lgkmcnt(0)" ::: "memory");

    // --- A fragments --------------------------------------------------------
    const int q   = lane >> 4;
    const int col = lane & 15;
    const int q4  = q * 4;
    const int ucol = col >> 3;     // u-parity for w01/w10 paths
    bf16x8 aF[4][2];
    #pragma unroll
    for (int mt = 0; mt < 4; ++mt)
        #pragma unroll
        for (int ks = 0; ks < 2; ++ks)
            aF[mt][ks] = *(const bf16x8*)(my + (mt*16 + col)*144 + q*16 + ks*64);
    asm volatile("s_waitcnt lgkmcnt(0)" ::: "memory");   // aF reads done before overwrite

    // --- stage x0t + dott (h region now dead) ------------------------------
    #pragma unroll
    for (int u = 0; u < 16; ++u) shf[u*64 + lane] = x0[u];
    #pragma unroll
    for (int u = 0; u < 8;  ++u) shf[1024 + u*64 + lane] = dot[u];
    asm volatile("s_waitcnt lgkmcnt(0)" ::: "memory");

    // --- distributed accumulators (C-layout: lane has edges 4q+r, col) ------
    f32x4 out0d[4], t01d[4], o1bd[4][3];
    #pragma unroll
    for (int m = 0; m < 4; ++m) {
        out0d[m] = (f32x4){0.f,0.f,0.f,0.f};
        t01d[m]  = (f32x4){0.f,0.f,0.f,0.f};
        #pragma unroll
        for (int k = 0; k < 3; ++k) o1bd[m][k] = (f32x4){0.f,0.f,0.f,0.f};
    }

#define MFMA8() \
    f32x4 wr0 = {0.f,0.f,0.f,0.f}, wr1 = {0.f,0.f,0.f,0.f}; \
    f32x4 wr2 = {0.f,0.f,0.f,0.f}, wr3 = {0.f,0.f,0.f,0.f}; \
    wr0 = __builtin_amdgcn_mfma_f32_16x16x32_bf16(aF[0][0], bc0, wr0, 0,0,0); \
    wr1 = __builtin_amdgcn_mfma_f32_16x16x32_bf16(aF[1][0], bc0, wr1, 0,0,0); \
    wr2 = __builtin_amdgcn_mfma_f32_16x16x32_bf16(aF[2][0], bc0, wr2, 0,0,0); \
    wr3 = __builtin_amdgcn_mfma_f32_16x16x32_bf16(aF[3][0], bc0, wr3, 0,0,0); \
    wr0 = __builtin_amdgcn_mfma_f32_16x16x32_bf16(aF[0][1], bc1, wr0, 0,0,0); \
    wr1 = __builtin_amdgcn_mfma_f32_16x16x32_bf16(aF[1][1], bc1, wr1, 0,0,0); \
    wr2 = __builtin_amdgcn_mfma_f32_16x16x32_bf16(aF[2][1], bc1, wr2, 0,0,0); \
    wr3 = __builtin_amdgcn_mfma_f32_16x16x32_bf16(aF[3][1], bc1, wr3, 0,0,0);

#define PRE(NT2) { b20 = wsBv[(NT2)*128 + lane]; b21 = wsBv[(NT2)*128 + 64 + lane]; }
#define ROT()    { bc0 = bn0; bc1 = bn1; bn0 = b20; bn1 = b21; }

// broadcast-read 4 x f32x4 from xT row BASEW and fma into ACC[0..3]
#define CONS4(ACC, BASEW) { \
    const float* xb_ = shf + (BASEW) + q4; \
    ACC[0] = fma4(wr0, *(const f32x4*)(xb_ +  0), ACC[0]); \
    ACC[1] = fma4(wr1, *(const f32x4*)(xb_ + 16), ACC[1]); \
    ACC[2] = fma4(wr2, *(const f32x4*)(xb_ + 32), ACC[2]); \
    ACC[3] = fma4(wr3, *(const f32x4*)(xb_ + 48), ACC[3]); }

    // --- w00: chunks 0..15 (cols u*16+col) ---------------------------------
    #pragma unroll
    for (int u = 0; u < 16; ++u) {
        PRE(u + 2);                         // 2..17
        MFMA8();
        CONS4(out0d, u * 64);
        ROT();
    }
    // --- w01: chunks 16..23 (u = 2t+ucol, v = col&7) -----------------------
    #pragma unroll
    for (int t = 0; t < 8; ++t) {
        PRE(t < 6 ? 18 + t : 28 + (t - 6)); // 18..23, 28, 29
        MFMA8();
        CONS4(t01d, (2*t + ucol) * 64);
        ROT();
    }
    // resolve u-parity partials: lanes col and col^8 hold complementary sums
    #pragma unroll
    for (int m = 0; m < 4; ++m)
        #pragma unroll
        for (int rr = 0; rr < 4; ++rr)
            t01d[m][rr] += __shfl_xor(t01d[m][rr], 8);

    // --- w11: chunks 28..35 (cols u*16+col, scalar = dot) ------------------
    #pragma unroll
    for (int u = 0; u < 8; ++u) {
        PRE(u < 6 ? 30 + u : 24 + (u - 6)); // 30..35, 24, 25
        MFMA8();
        CONS4(out0d, 1024 + u * 64);
        ROT();
    }

    // --- restage x1t (x0t/dott dead); drain reads first --------------------
    asm volatile("s_waitcnt lgkmcnt(0)" ::: "memory");
    #pragma unroll
    for (int u = 0; u < 8; ++u)
        #pragma unroll
        for (int k = 0; k < 3; ++k)
            shf[(u*3 + k)*64 + lane] = x1[3*u + k];
    asm volatile("s_waitcnt lgkmcnt(0)" ::: "memory");

    // --- w10: chunks 24..27 (u = 2t+ucol, v = col&7, vector over k) --------
    #pragma unroll
    for (int t = 0; t < 4; ++t) {
        if (t < 2) PRE(26 + t);             // 26, 27
        MFMA8();
        const int ub = (2*t + ucol) * 192 + q4;
#define W10_MT(MT, WR) { \
        f32x4 xv0 = *(const f32x4*)(shf + ub +   0 + 16*(MT)); \
        f32x4 xv1 = *(const f32x4*)(shf + ub +  64 + 16*(MT)); \
        f32x4 xv2 = *(const f32x4*)(shf + ub + 128 + 16*(MT)); \
        o1bd[MT][0] = fma4(WR, xv0, o1bd[MT][0]); \
        o1bd[MT][1] = fma4(WR, xv1, o1bd[MT][1]); \
        o1bd[MT][2] = fma4(WR, xv2, o1bd[MT][2]); }
        W10_MT(0, wr0) W10_MT(1, wr1) W10_MT(2, wr2) W10_MT(3, wr3)
#undef W10_MT
        ROT();
    }
#undef CONS4
#undef PRE
#undef ROT
#undef MFMA8
    // resolve o1bd u-parity partials
    #pragma unroll
    for (int m = 0; m < 4; ++m)
        #pragma unroll
        for (int k = 0; k < 3; ++k)
            #pragma unroll
            for (int rr = 0; rr < 4; ++rr)
                o1bd[m][k][rr] += __shfl_xor(o1bd[m][k][rr], 8);

    // --- epilogue ----------------------------------------------------------
    const float FXP_S = (1.0f / (32.0f * 4.898979485566356f)) * FXP32_SCALE;

    // E1: out0 (v=col) + sh + dst, stride 20 words; drain w10 reads first
    asm volatile("s_waitcnt lgkmcnt(0)" ::: "memory");
    #pragma unroll
    for (int m = 0; m < 4; ++m)
        #pragma unroll
        for (int rr = 0; rr < 4; ++rr)
            shf[(16*m + 4*q + rr) * 20 + col] = out0d[m][rr];
    shf[lane*20 + 16] = shx;
    shf[lane*20 + 17] = shy;
    shf[lane*20 + 18] = shz;
    ((int*)shf)[lane*20 + 19] = d;
    asm volatile("s_waitcnt lgkmcnt(0)" ::: "memory");

    #pragma unroll 4
    for (int it = 0; it < 16; ++it) {
        int p  = it * 64 + lane;
        int ee = p >> 4;
        int c  = p & 15;
        float v = shf[ee*20 + c];
        int dd  = ((int*)shf)[ee*20 + 19];
        atomicAdd(f_out_i + (size_t)dd*40 + c, __float2int_rn(v * FXP_S));
    }

    // E2: fused out1 = t01[v]*sh[k] + o1b[v][k], 24 words + dst, stride 28
    float shr[4][4][3];
    #pragma unroll
    for (int m = 0; m < 4; ++m)
        #pragma unroll
        for (int rr = 0; rr < 4; ++rr) {
            int eb = (16*m + 4*q + rr) * 20 + 16;
            shr[m][rr][0] = shf[eb + 0];
            shr[m][rr][1] = shf[eb + 1];
            shr[m][rr][2] = shf[eb + 2];
        }
    asm volatile("s_waitcnt lgkmcnt(0)" ::: "memory");   // shr reads done before overwrite
    if (col < 8) {
        #pragma unroll
        for (int m = 0; m < 4; ++m)
            #pragma unroll
            for (int rr = 0; rr < 4; ++rr)
                #pragma unroll
                for (int k = 0; k < 3; ++k) {
                    float fv = fmaf(t01d[m][rr], shr[m][rr][k], o1bd[m][k][rr]);
                    shf[(16*m + 4*q + rr) * 28 + 3*col + k] = fv;
                }
    }
    ((int*)shf)[lane*28 + 27] = d;
    asm volatile("s_waitcnt lgkmcnt(0)" ::: "memory");

    #pragma unroll 4
    for (int it = 0; it < 24; ++it) {
        int p  = it * 64 + lane;
        int ee = (p * 10923) >> 18;      // p / 24, exact for p < 1536
        int c  = p - ee * 24;
        float v = shf[ee*28 + c];
        int dd  = ((int*)shf)[ee*28 + 27];
        atomicAdd(f_out_i + (size_t)dd*40 + 16 + c, __float2int_rn(v * FXP_S));
    }

    // drain epilogue LDS reads before the next tile's h-writes reuse smem
    asm volatile("s_waitcnt lgkmcnt(0)" ::: "memory");
}

// ---------------------------------------------------------------------------
// FUSED cooperative kernel: phase 0 (zero+pack) -> sync -> phase 1 (conv,
// grid-stride over tiles) -> sync -> phase 2 (finalize). One dispatch
// replaces three (saves ~2 launch gaps, ~40-60 us of the 69 us non-conv
// time). Co-residency guaranteed: __launch_bounds__(64,2) => >=8 one-wave
// blocks/CU; grid = 2048 = 8 x 256 CUs. LDS 8 x 9216 = 73 KB/CU.
// ---------------------------------------------------------------------------
__global__ __launch_bounds__(64, 2) void fused_kernel(
    const float* __restrict__ pos,
    const float* __restrict__ f_in,
    const int*   __restrict__ esrc,
    const int*   __restrict__ edst,
    const float* __restrict__ W1,
    const float* __restrict__ W2,
    unsigned short* __restrict__ wsB,
    unsigned* __restrict__ w1p,
    int*      __restrict__ f_out_i)
{
    __shared__ __align__(16) char smem[9216];
    const int lane = threadIdx.x;
    const int gid  = blockIdx.x * 64 + lane;
    const int nth  = gridDim.x * 64;

    // --- phase 0: zero d_out (int4 grid-stride) + pack W2/W1 ---------------
    {
        int4* outz = (int4*)f_out_i;
        const int n16 = (N_NODES * 40) / 4;          // 500,000
        for (int i = gid; i < n16; i += nth)
            outz[i] = make_int4(0, 0, 0, 0);
        for (int p = gid; p < 36864 + 512; p += nth)
            pack_item(p, W2, W1, wsB, w1p);
    }
    __threadfence();
    cg::this_grid().sync();

    // --- phase 1: conv tiles, grid-stride ------------------------------------
    for (int tile = blockIdx.x; tile < N_TILES; tile += gridDim.x)
        conv_tile(tile, lane, pos, f_in, esrc, edst, w1p, wsB, f_out_i, smem);

    __threadfence();
    cg::this_grid().sync();

    // --- phase 2: finalize int32 fxp -> float (in place, bitcast) -----------
    {
        float4* p4 = (float4*)f_out_i;
        const int n16 = (N_NODES * 40) / 4;
        for (int i = gid; i < n16; i += nth)
            p4[i] = finalize4(p4[i]);
    }
}

// ---------------------------------------------------------------------------
// Fallback path (r9-verified 3-kernel pipeline), used only if cooperative
// launch is unsupported.
// ---------------------------------------------------------------------------
__global__ void setup_kernel(const float* __restrict__ W2,
                             const float* __restrict__ W1,
                             unsigned short* __restrict__ wsB,
                             unsigned* __restrict__ w1p,
                             int4* __restrict__ out, int n16) {
    int gid = blockIdx.x * 256 + threadIdx.x;
    for (int i = gid; i < n16; i += gridDim.x * 256)
        out[i] = make_int4(0, 0, 0, 0);
    if (gid < 36864 + 512) pack_item(gid, W2, W1, wsB, w1p);
}

__global__ void finalize_kernel(float4* p, int n4) {
    int i = blockIdx.x * blockDim.x + threadIdx.x;
    if (i < n4) p[i] = finalize4(p[i]);
}

__global__ __launch_bounds__(64, 2) void conv_kernel(
    const float* __restrict__ pos,
    const float* __restrict__ f_in,
    const int*   __restrict__ esrc,
    const int*   __restrict__ edst,
    const unsigned* __restrict__ w1p,
    const unsigned short* __restrict__ wsB,
    int*         __restrict__ f_out_i)
{
    __shared__ __align__(16) char smem[9216];
    conv_tile(blockIdx.x, threadIdx.x, pos, f_in, esrc, edst, w1p, wsB,
              f_out_i, smem);
}

extern "C" void kernel_launch(void* const* d_in, const int* in_sizes, int n_in,
                              void* d_out, int out_size, void* d_ws, size_t ws_size,
                              hipStream_t stream) {
    const float* pos  = (const float*)d_in[0];
    const float* f_in = (const float*)d_in[1];
    const int*   esrc = (const int*)  d_in[2];
    const int*   edst = (const int*)  d_in[3];
    const float* W1   = (const float*)d_in[4];
    const float* W2   = (const float*)d_in[5];
    float* out = (float*)d_out;

    unsigned short* wsB = (unsigned short*)d_ws;
    unsigned*       w1p = (unsigned*)((char*)d_ws + WSB_BYTES);
    int*            outi = (int*)out;

    const int nOut = N_NODES * 40;            // 2,000,000
    const int n16  = nOut / 4;                // 500,000 int4s

    // Decide cooperative capability once (host-side queries only; no stream
    // ops, capture-safe). __launch_bounds__(64,2) guarantees >=8 blocks/CU,
    // but verify via the occupancy API and clamp the grid.
    static int coop_blocks = -2;              // -2 = undetermined
    if (coop_blocks == -2) {
        int dev = 0, coop = 0, nblk = 0;
        if (hipGetDevice(&dev) == hipSuccess &&
            hipDeviceGetAttribute(&coop, hipDeviceAttributeCooperativeLaunch,
                                  dev) == hipSuccess && coop) {
            if (hipOccupancyMaxActiveBlocksPerMultiprocessor(
                    &nblk, (const void*)fused_kernel, 64, 0) == hipSuccess &&
                nblk > 0) {
                coop_blocks = nblk * 256;
                if (coop_blocks > 2048) coop_blocks = 2048;
            } else coop_blocks = -1;
        } else coop_blocks = -1;
    }

    if (coop_blocks > 0) {
        void* args[] = {(void*)&pos, (void*)&f_in, (void*)&esrc, (void*)&edst,
                        (void*)&W1, (void*)&W2, (void*)&wsB, (void*)&w1p,
                        (void*)&outi};
        hipError_t err = hipLaunchCooperativeKernel(
            (const void*)fused_kernel, dim3(coop_blocks), dim3(64),
            args, 0, stream);
        if (err == hipSuccess) return;
        (void)hipGetLastError();
        coop_blocks = -1;                     // fall through + remember
    }

    // fallback: r9-verified 3-kernel path
    setup_kernel<<<256, 256, 0, stream>>>(W2, W1, wsB, w1p, (int4*)out, n16);
    conv_kernel<<<N_TILES, 64, 0, stream>>>(pos, f_in, esrc, edst, w1p, wsB, outi);
    finalize_kernel<<<(n16 + 255) / 256, 256, 0, stream>>>((float4*)out, n16);
}

// Round 14
// 229.964 us; speedup vs baseline: 4.1042x; 4.1042x over previous
//
#include <hip/hip_runtime.h>
#include <hip/hip_fp16.h>

#define N_NODES 50000
#define N_EDGES 800000

typedef short  bf16x8 __attribute__((ext_vector_type(8)));
typedef float  f32x4  __attribute__((ext_vector_type(4)));
typedef _Float16 h16x2 __attribute__((ext_vector_type(2)));

// 32-bit fixed point in d_out: scale 2^22. VALIDATED rounds 8/9 (tripwire-safe:
// integer atomics associative+commutative; absmax 0.015625).
#define FXP32_SCALE 4194304.0f                 // 2^22
#define FXP32_INV   2.384185791015625e-07f     // 2^-22

#define WSB_BYTES   (36864 * 2)                // 73,728 B
#define W1P_BYTES   (512 * 4)                  // 2,048 B
#define FB_WORDS    (N_NODES * 20)             // 1,000,000 u32 (bf16-packed f_in)

__device__ __forceinline__ unsigned short f2bf(float f) {
    unsigned u = __float_as_uint(f);
    u += 0x7FFF + ((u >> 16) & 1);          // RNE
    return (unsigned short)(u >> 16);
}

__device__ __forceinline__ unsigned pack2bf(float a, float b) {
    return (unsigned)f2bf(a) | ((unsigned)f2bf(b) << 16);
}

__device__ __forceinline__ f32x4 fma4(f32x4 a, f32x4 b, f32x4 c) {
    f32x4 r;
    r[0] = fmaf(a[0], b[0], c[0]);
    r[1] = fmaf(a[1], b[1], c[1]);
    r[2] = fmaf(a[2], b[2], c[2]);
    r[3] = fmaf(a[3], b[3], c[3]);
    return r;
}

#if __has_builtin(__builtin_amdgcn_fdot2)
__device__ __forceinline__ float FDOT2(h16x2 a, h16x2 b, float c) {
    return __builtin_amdgcn_fdot2(a, b, c, false);
}
#else
__device__ __forceinline__ float FDOT2(h16x2 a, h16x2 b, float c) {
    return fmaf((float)a.x, (float)b.x, fmaf((float)a.y, (float)b.y, c));
}
#endif

// ---------------------------------------------------------------------------
// setup: zero d_out (grid-stride) + pack W2 bf16 B-frags + pack W1 f16
// k-pairs + pack f_in -> bf16 pairs (fb). Node stride is 40 f32 = 20 u32,
// so fb is LINEAR: fb[i] = pack(f_in[2i], f_in[2i+1]), no div needed.
// ---------------------------------------------------------------------------
__global__ void setup_kernel(const float* __restrict__ W2,
                             const float* __restrict__ W1,
                             const float* __restrict__ f_in,
                             unsigned short* __restrict__ wsB,
                             unsigned* __restrict__ w1p,
                             unsigned* __restrict__ fb,
                             int4* __restrict__ out, int n16) {
    int gid = blockIdx.x * 256 + threadIdx.x;
    int nth = gridDim.x * 256;
    for (int i = gid; i < n16; i += nth)
        out[i] = make_int4(0, 0, 0, 0);
    for (int i = gid; i < FB_WORDS; i += nth)
        fb[i] = pack2bf(f_in[2*i], f_in[2*i+1]);
    if (gid < 36864) {
        int j    = gid & 7;
        int lane = (gid >> 3) & 63;
        int ks   = (gid >> 9) & 1;
        int nt   = gid >> 10;
        int k = ks * 32 + (lane >> 4) * 8 + j;
        int n = nt * 16 + (lane & 15);
        wsB[gid] = f2bf(W2[k * 576 + n]);
    } else if (gid < 36864 + 512) {
        int idx = gid - 36864;
        int kk  = idx >> 6;
        int i   = idx & 63;
        __half lo = __float2half(W1[(2*kk)     * 64 + i]);
        __half hi = __float2half(W1[(2*kk + 1) * 64 + i]);
        w1p[idx] = (unsigned)__half_as_ushort(lo)
                 | ((unsigned)__half_as_ushort(hi) << 16);
    }
}

// ---------------------------------------------------------------------------
// finalize: in-place int32 fxp -> float in d_out. SINGLE pointer type +
// bitcast: no aliasing UB (validated rounds 8/9).
// ---------------------------------------------------------------------------
__global__ void finalize_kernel(float4* p, int n4) {
    int i = blockIdx.x * blockDim.x + threadIdx.x;
    if (i < n4) {
        float4 v = p[i];
        float4 f;
        f.x = (float)__float_as_int(v.x) * FXP32_INV;
        f.y = (float)__float_as_int(v.y) * FXP32_INV;
        f.z = (float)__float_as_int(v.z) * FXP32_INV;
        f.w = (float)__float_as_int(v.w) * FXP32_INV;
        p[i] = f;
    }
}

// ---------------------------------------------------------------------------
// fused conv. v14 = v9 VERBATIM except the x-gather reads bf16-packed fb:
// 5 x uint4 (80 B/lane) instead of 10 x float4 (160 B/lane), halving the
// dominant FETCH component (f_in gather, ~128 MB ideal) and the load count
// on the wave-start serial chain (esrc/edst -> f_in gather). bf16->f32
// unpack is an exact bit shift; the one RNE rounding on x is the same
// error class as the existing h/W2 bf16 roundings (absmax headroom 5x).
// REFUTED levers (kept out): VALU count (r10), atomic op count (r11),
// 3-waves/SIMD (r12 spills), coop fusion (r13 spills).
// ---------------------------------------------------------------------------
__global__ __launch_bounds__(64, 2) void conv_kernel(
    const float* __restrict__ pos,
    const unsigned* __restrict__ fb,
    const int*   __restrict__ esrc,
    const int*   __restrict__ edst,
    const unsigned* __restrict__ w1p,
    const unsigned short* __restrict__ wsB,
    int*         __restrict__ f_out_i)
{
    // 9216 B region, reused in phases (wave-local lgkmcnt only):
    //   ph1: h-stage 64x72 bf16 (stride 144 B)          = 9216 B
    //   ph2: x0t 16x64 f32 [0,4096) + dott 8x64 [4096,6144)
    //   ph3: x1t 24x64 f32 [0,6144)
    //   ph4: E1 out0+sh+dst, stride 20 f32              = 5120 B
    //   ph5: E2 out1-fused+dst, stride 28 f32           = 7168 B
    __shared__ __align__(16) char smem[9216];

    const int lane = threadIdx.x;
    const int e    = blockIdx.x * 64 + lane;
    char*  my  = smem;
    float* shf = (float*)smem;

    const int s = esrc[e];
    const int d = edst[e];

    // early B prefetch: chunks 0 and 1
    const bf16x8* wsBv = (const bf16x8*)wsB;
    bf16x8 bc0 = wsBv[lane],        bc1 = wsBv[64 + lane];
    bf16x8 bn0 = wsBv[128 + lane],  bn1 = wsBv[192 + lane];
    bf16x8 b20, b21;

    // --- geometry -----------------------------------------------------------
    float px = pos[3*d+0] - pos[3*s+0];
    float py = pos[3*d+1] - pos[3*s+1];
    float pz = pos[3*d+2] - pos[3*s+2];
    float r  = sqrtf(px*px + py*py + pz*pz + 1e-12f);
    float inv_r = __builtin_amdgcn_rcpf(r);
    float ux = px*inv_r, uy = py*inv_r, uz = pz*inv_r;
    const float SQ3 = 1.7320508075688772f;
    float shx = SQ3*ux, shy = SQ3*uy, shz = SQ3*uz;

    // --- x = fb[src] (bf16-packed, 5 x uint4) -------------------------------
    float x0[16], x1[24], dot[8];
    {
        const uint4* xg4 = reinterpret_cast<const uint4*>(fb + (size_t)s * 20);
        uint4 v0 = xg4[0], v1 = xg4[1], v2 = xg4[2], v3 = xg4[3], v4 = xg4[4];
        unsigned xw[20] = {v0.x, v0.y, v0.z, v0.w,
                           v1.x, v1.y, v1.z, v1.w,
                           v2.x, v2.y, v2.z, v2.w,
                           v3.x, v3.y, v3.z, v3.w,
                           v4.x, v4.y, v4.z, v4.w};
        float xr[40];
        #pragma unroll
        for (int i = 0; i < 20; ++i) {
            xr[2*i]   = __uint_as_float(xw[i] << 16);          // low bf16
            xr[2*i+1] = __uint_as_float(xw[i] & 0xffff0000u);  // high bf16
        }
        #pragma unroll
        for (int i = 0; i < 16; ++i) x0[i] = xr[i];
        #pragma unroll
        for (int i = 0; i < 24; ++i) x1[i] = xr[16+i];
        #pragma unroll
        for (int u = 0; u < 8; ++u)
            dot[u] = x1[3*u+0]*ux + x1[3*u+1]*uy + x1[3*u+2]*uz;  // = inv_s3*(x1.sh1)
    }

    // --- radial embedding (dense, verified) ---------------------------------
    const float A = 1.14136f * 7.38905609893065f;   // 1.14136 * e^2
    const float inv_step = 17.0f / 5.0f;
    float emb[16];
    #pragma unroll
    for (int k = 0; k < 16; ++k) {
        float dd  = r * inv_step - (float)(k + 1);
        float d2v = dd * dd;
        float arg = -2.0f * __builtin_amdgcn_rcpf(1.0f - d2v);
        float val = A * __expf(arg);
        emb[k] = (d2v < 1.0f) ? val : 0.0f;
    }

    // --- h = silu(emb @ W1) via f16 dot2 (verified v7/v9) --------------------
    unsigned ep[8];
    #pragma unroll
    for (int kk = 0; kk < 8; ++kk) {
        __half lo = __float2half(emb[2*kk]);
        __half hi = __float2half(emb[2*kk+1]);
        ep[kk] = (unsigned)__half_as_ushort(lo)
               | ((unsigned)__half_as_ushort(hi) << 16);
    }
    float h[64];
    #pragma unroll
    for (int i = 0; i < 64; ++i) h[i] = 0.f;
    #pragma unroll
    for (int kk = 0; kk < 8; ++kk) {
        h16x2 ev = __builtin_bit_cast(h16x2, ep[kk]);
        const unsigned* wrow = w1p + kk * 64;
        #pragma unroll
        for (int i = 0; i < 64; ++i) {
            h16x2 wv = __builtin_bit_cast(h16x2, wrow[i]);
            h[i] = FDOT2(ev, wv, h[i]);
        }
    }
    #pragma unroll
    for (int i = 0; i < 64; ++i) {
        float z = h[i];
        h[i] = z * __builtin_amdgcn_rcpf(1.0f + __expf(-z));
    }

    // --- stage h -> LDS [edge][k] bf16, row stride 144 B -------------------
    {
        unsigned int hp[32];
        #pragma unroll
        for (int i = 0; i < 32; ++i)
            hp[i] = (unsigned)f2bf(h[2*i]) | ((unsigned)f2bf(h[2*i+1]) << 16);
        uint4* hrow = (uint4*)(my + lane * 144);
        #pragma unroll
        for (int g = 0; g < 8; ++g)
            hrow[g] = make_uint4(hp[4*g], hp[4*g+1], hp[4*g+2], hp[4*g+3]);
    }
    asm volatile("s_waitcnt lgkmcnt(0)" ::: "memory");

    // --- A fragments --------------------------------------------------------
    const int q   = lane >> 4;
    const int col = lane & 15;
    const int q4  = q * 4;
    const int ucol = col >> 3;     // u-parity for w01/w10 paths
    bf16x8 aF[4][2];
    #pragma unroll
    for (int mt = 0; mt < 4; ++mt)
        #pragma unroll
        for (int ks = 0; ks < 2; ++ks)
            aF[mt][ks] = *(const bf16x8*)(my + (mt*16 + col)*144 + q*16 + ks*64);
    asm volatile("s_waitcnt lgkmcnt(0)" ::: "memory");   // aF reads done before overwrite

    // --- stage x0t + dott (h region now dead) ------------------------------
    #pragma unroll
    for (int u = 0; u < 16; ++u) shf[u*64 + lane] = x0[u];
    #pragma unroll
    for (int u = 0; u < 8;  ++u) shf[1024 + u*64 + lane] = dot[u];
    asm volatile("s_waitcnt lgkmcnt(0)" ::: "memory");

    // --- distributed accumulators (C-layout: lane has edges 4q+r, col) ------
    f32x4 out0d[4], t01d[4], o1bd[4][3];
    #pragma unroll
    for (int m = 0; m < 4; ++m) {
        out0d[m] = (f32x4){0.f,0.f,0.f,0.f};
        t01d[m]  = (f32x4){0.f,0.f,0.f,0.f};
        #pragma unroll
        for (int k = 0; k < 3; ++k) o1bd[m][k] = (f32x4){0.f,0.f,0.f,0.f};
    }

#define MFMA8() \
    f32x4 wr0 = {0.f,0.f,0.f,0.f}, wr1 = {0.f,0.f,0.f,0.f}; \
    f32x4 wr2 = {0.f,0.f,0.f,0.f}, wr3 = {0.f,0.f,0.f,0.f}; \
    wr0 = __builtin_amdgcn_mfma_f32_16x16x32_bf16(aF[0][0], bc0, wr0, 0,0,0); \
    wr1 = __builtin_amdgcn_mfma_f32_16x16x32_bf16(aF[1][0], bc0, wr1, 0,0,0); \
    wr2 = __builtin_amdgcn_mfma_f32_16x16x32_bf16(aF[2][0], bc0, wr2, 0,0,0); \
    wr3 = __builtin_amdgcn_mfma_f32_16x16x32_bf16(aF[3][0], bc0, wr3, 0,0,0); \
    wr0 = __builtin_amdgcn_mfma_f32_16x16x32_bf16(aF[0][1], bc1, wr0, 0,0,0); \
    wr1 = __builtin_amdgcn_mfma_f32_16x16x32_bf16(aF[1][1], bc1, wr1, 0,0,0); \
    wr2 = __builtin_amdgcn_mfma_f32_16x16x32_bf16(aF[2][1], bc1, wr2, 0,0,0); \
    wr3 = __builtin_amdgcn_mfma_f32_16x16x32_bf16(aF[3][1], bc1, wr3, 0,0,0);

#define PRE(NT2) { b20 = wsBv[(NT2)*128 + lane]; b21 = wsBv[(NT2)*128 + 64 + lane]; }
#define ROT()    { bc0 = bn0; bc1 = bn1; bn0 = b20; bn1 = b21; }

// broadcast-read 4 x f32x4 from xT row BASEW and fma into ACC[0..3]
#define CONS4(ACC, BASEW) { \
    const float* xb_ = shf + (BASEW) + q4; \
    ACC[0] = fma4(wr0, *(const f32x4*)(xb_ +  0), ACC[0]); \
    ACC[1] = fma4(wr1, *(const f32x4*)(xb_ + 16), ACC[1]); \
    ACC[2] = fma4(wr2, *(const f32x4*)(xb_ + 32), ACC[2]); \
    ACC[3] = fma4(wr3, *(const f32x4*)(xb_ + 48), ACC[3]); }

    // --- w00: chunks 0..15 (cols u*16+col) ---------------------------------
    #pragma unroll
    for (int u = 0; u < 16; ++u) {
        PRE(u + 2);                         // 2..17
        MFMA8();
        CONS4(out0d, u * 64);
        ROT();
    }
    // --- w01: chunks 16..23 (u = 2t+ucol, v = col&7) -----------------------
    #pragma unroll
    for (int t = 0; t < 8; ++t) {
        PRE(t < 6 ? 18 + t : 28 + (t - 6)); // 18..23, 28, 29
        MFMA8();
        CONS4(t01d, (2*t + ucol) * 64);
        ROT();
    }
    // resolve u-parity partials: lanes col and col^8 hold complementary sums
    #pragma unroll
    for (int m = 0; m < 4; ++m)
        #pragma unroll
        for (int rr = 0; rr < 4; ++rr)
            t01d[m][rr] += __shfl_xor(t01d[m][rr], 8);

    // --- w11: chunks 28..35 (cols u*16+col, scalar = dot) ------------------
    #pragma unroll
    for (int u = 0; u < 8; ++u) {
        PRE(u < 6 ? 30 + u : 24 + (u - 6)); // 30..35, 24, 25
        MFMA8();
        CONS4(out0d, 1024 + u * 64);
        ROT();
    }

    // --- restage x1t (x0t/dott dead); drain reads first --------------------
    asm volatile("s_waitcnt lgkmcnt(0)" ::: "memory");
    #pragma unroll
    for (int u = 0; u < 8; ++u)
        #pragma unroll
        for (int k = 0; k < 3; ++k)
            shf[(u*3 + k)*64 + lane] = x1[3*u + k];
    asm volatile("s_waitcnt lgkmcnt(0)" ::: "memory");

    // --- w10: chunks 24..27 (u = 2t+ucol, v = col&7, vector over k) --------
    #pragma unroll
    for (int t = 0; t < 4; ++t) {
        if (t < 2) PRE(26 + t);             // 26, 27
        MFMA8();
        const int ub = (2*t + ucol) * 192 + q4;
#define W10_MT(MT, WR) { \
        f32x4 xv0 = *(const f32x4*)(shf + ub +   0 + 16*(MT)); \
        f32x4 xv1 = *(const f32x4*)(shf + ub +  64 + 16*(MT)); \
        f32x4 xv2 = *(const f32x4*)(shf + ub + 128 + 16*(MT)); \
        o1bd[MT][0] = fma4(WR, xv0, o1bd[MT][0]); \
        o1bd[MT][1] = fma4(WR, xv1, o1bd[MT][1]); \
        o1bd[MT][2] = fma4(WR, xv2, o1bd[MT][2]); }
        W10_MT(0, wr0) W10_MT(1, wr1) W10_MT(2, wr2) W10_MT(3, wr3)
#undef W10_MT
        ROT();
    }
#undef CONS4
#undef PRE
#undef ROT
#undef MFMA8
    // resolve o1bd u-parity partials
    #pragma unroll
    for (int m = 0; m < 4; ++m)
        #pragma unroll
        for (int k = 0; k < 3; ++k)
            #pragma unroll
            for (int rr = 0; rr < 4; ++rr)
                o1bd[m][k][rr] += __shfl_xor(o1bd[m][k][rr], 8);

    // --- epilogue ----------------------------------------------------------
    const float FXP_S = (1.0f / (32.0f * 4.898979485566356f)) * FXP32_SCALE;

    // E1: out0 (v=col) + sh + dst, stride 20 words; drain w10 reads first
    asm volatile("s_waitcnt lgkmcnt(0)" ::: "memory");
    #pragma unroll
    for (int m = 0; m < 4; ++m)
        #pragma unroll
        for (int rr = 0; rr < 4; ++rr)
            shf[(16*m + 4*q + rr) * 20 + col] = out0d[m][rr];
    shf[lane*20 + 16] = shx;
    shf[lane*20 + 17] = shy;
    shf[lane*20 + 18] = shz;
    ((int*)shf)[lane*20 + 19] = d;
    asm volatile("s_waitcnt lgkmcnt(0)" ::: "memory");

    #pragma unroll 4
    for (int it = 0; it < 16; ++it) {
        int p  = it * 64 + lane;
        int ee = p >> 4;
        int c  = p & 15;
        float v = shf[ee*20 + c];
        int dd  = ((int*)shf)[ee*20 + 19];
        atomicAdd(f_out_i + (size_t)dd*40 + c, __float2int_rn(v * FXP_S));
    }

    // E2: fused out1 = t01[v]*sh[k] + o1b[v][k], 24 words + dst, stride 28
    float shr[4][4][3];
    #pragma unroll
    for (int m = 0; m < 4; ++m)
        #pragma unroll
        for (int rr = 0; rr < 4; ++rr) {
            int eb = (16*m + 4*q + rr) * 20 + 16;
            shr[m][rr][0] = shf[eb + 0];
            shr[m][rr][1] = shf[eb + 1];
            shr[m][rr][2] = shf[eb + 2];
        }
    asm volatile("s_waitcnt lgkmcnt(0)" ::: "memory");   // shr reads done before overwrite
    if (col < 8) {
        #pragma unroll
        for (int m = 0; m < 4; ++m)
            #pragma unroll
            for (int rr = 0; rr < 4; ++rr)
                #pragma unroll
                for (int k = 0; k < 3; ++k) {
                    float fv = fmaf(t01d[m][rr], shr[m][rr][k], o1bd[m][k][rr]);
                    shf[(16*m + 4*q + rr) * 28 + 3*col + k] = fv;
                }
    }
    ((int*)shf)[lane*28 + 27] = d;
    asm volatile("s_waitcnt lgkmcnt(0)" ::: "memory");

    #pragma unroll 4
    for (int it = 0; it < 24; ++it) {
        int p  = it * 64 + lane;
        int ee = (p * 10923) >> 18;      // p / 24, exact for p < 1536
        int c  = p - ee * 24;
        float v = shf[ee*28 + c];
        int dd  = ((int*)shf)[ee*28 + 27];
        atomicAdd(f_out_i + (size_t)dd*40 + 16 + c, __float2int_rn(v * FXP_S));
    }
}

extern "C" void kernel_launch(void* const* d_in, const int* in_sizes, int n_in,
                              void* d_out, int out_size, void* d_ws, size_t ws_size,
                              hipStream_t stream) {
    const float* pos  = (const float*)d_in[0];
    const float* f_in = (const float*)d_in[1];
    const int*   esrc = (const int*)  d_in[2];
    const int*   edst = (const int*)  d_in[3];
    const float* W1   = (const float*)d_in[4];
    const float* W2   = (const float*)d_in[5];
    float* out = (float*)d_out;

    unsigned short* wsB = (unsigned short*)d_ws;
    unsigned*       w1p = (unsigned*)((char*)d_ws + WSB_BYTES);
    unsigned*       fb  = (unsigned*)((char*)d_ws + WSB_BYTES + W1P_BYTES);

    const int nOut = N_NODES * 40;            // 2,000,000
    const int n16  = nOut / 4;                // 500,000 int4s

    // setup: zero d_out + pack W2/W1/f_in (one launch)
    setup_kernel<<<512, 256, 0, stream>>>(W2, W1, f_in, wsB, w1p, fb,
                                          (int4*)out, n16);

    // conv: 1-wave blocks, int32 fxp atomics into d_out
    conv_kernel<<<N_EDGES / 64, 64, 0, stream>>>(
        pos, fb, esrc, edst, w1p, wsB, (int*)out);

    // finalize: in-place int32 -> float (single pointer, no aliasing UB)
    finalize_kernel<<<(n16 + 255) / 256, 256, 0, stream>>>((float4*)out, n16);
}